// Round 4
// baseline (263.021 us; speedup 1.0000x reference)
//
#include <hip/hip_runtime.h>

namespace {

constexpr int kNY  = 512;
constexpr int kNT  = 128;
constexpr int kC   = 128;
constexpr int kEOS = 1;
constexpr int kNW  = 127;     // W rows consumed (0..126); row 127 never used
constexpr int kCH  = 16;      // rows per LDS chunk
constexpr int kNCH = 8;       // ceil(127/16)

// ---------------------------------------------------------------------------
// DPP helpers (pure builtins, no inline asm anywhere in this file).
// ---------------------------------------------------------------------------
template <int CTRL, int RM>
__device__ __forceinline__ float dppf(float src, float old) {
  return __int_as_float(__builtin_amdgcn_update_dpp(
      __float_as_int(old), __float_as_int(src), CTRL, RM, 0xF, false));
}

// value of `v` in lane-1 (lane 0 -> 0.0f)
__device__ __forceinline__ float lane_prev(float v, int lane) {
  float s1  = dppf<0x111, 0xF>(v, 0.0f);   // row_shr:1 (within 16)
  float b15 = dppf<0x142, 0xA>(v, 0.0f);   // lanes 16-31<-15, 48-63<-47
  float b31 = dppf<0x143, 0x4>(v, 0.0f);   // lanes 32-47<-31
  float r = s1;
  r = (lane == 16 || lane == 48) ? b15 : r;
  r = (lane == 32) ? b31 : r;
  return r;
}

// inclusive 64-lane affine scan of (A,B), then exclusive-A carry, apply.
__device__ __forceinline__ void scan_apply(const float (&Ap)[8],
                                           const float (&Bp)[8],
                                           float (&x)[8], float& xm1,
                                           int lane) {
  float SA = Ap[7], SB = Bp[7];
#define EP_SCAN_STEP(CTRL, RM)                                   \
  { float a = dppf<CTRL, RM>(SA, 0.0f);                          \
    float bb = dppf<CTRL, RM>(SB, 1.0f);                         \
    SA = fmaf(SB, a, SA); SB *= bb; }
  EP_SCAN_STEP(0x111, 0xF)   // row_shr:1
  EP_SCAN_STEP(0x112, 0xF)   // row_shr:2
  EP_SCAN_STEP(0x114, 0xF)   // row_shr:4
  EP_SCAN_STEP(0x118, 0xF)   // row_shr:8
  EP_SCAN_STEP(0x142, 0xA)   // row_bcast:15 -> rows 1,3
  EP_SCAN_STEP(0x143, 0xC)   // row_bcast:31 -> rows 2,3
#undef EP_SCAN_STEP
  const float carry = lane_prev(SA, lane);
#pragma unroll
  for (int c = 0; c < 8; ++c) x[c] = fmaf(Bp[c], carry, Ap[c]);
  xm1 = carry;
}

// One DP row. Quads hold (u[2k], v[2k], u[2k+1], v[2k+1]) for this lane's
// 8 columns j = lane*8 + c.
__device__ __forceinline__ void dp_row(const float4& q0, const float4& q1,
                                       const float4& q2, const float4& q3,
                                       bool eos, bool lane0,
                                       const float (&R2m)[8], float (&x)[8],
                                       float& xm1, int lane) {
  float u[8], v[8];
  u[0] = q0.x; v[0] = q0.y; u[1] = q0.z; v[1] = q0.w;
  u[2] = q1.x; v[2] = q1.y; u[3] = q1.z; v[3] = q1.w;
  u[4] = q2.x; v[4] = q2.y; u[5] = q2.z; v[5] = q2.w;
  u[6] = q3.x; v[6] = q3.y; u[7] = q3.z; v[7] = q3.w;

  float A[8], Bv[8], Ap[8], Bp[8];
  const float um1 = lane_prev(u[7], lane);  // U[lane*8 - 1]
  A[0]  = lane0 ? x[0] * v[1] : fmaf(x[0], v[0], xm1 * um1);
  Bv[0] = lane0 ? 0.0f : (eos ? 1.0f : R2m[0]);
#pragma unroll
  for (int c = 1; c < 8; ++c) {
    A[c]  = fmaf(x[c], v[c], x[c - 1] * u[c - 1]);
    Bv[c] = eos ? 1.0f : R2m[c];
  }
  Ap[0] = A[0]; Bp[0] = Bv[0];
#pragma unroll
  for (int c = 1; c < 8; ++c) {
    Ap[c] = fmaf(Bv[c], Ap[c - 1], A[c]);
    Bp[c] = Bv[c] * Bp[c - 1];
  }
  scan_apply(Ap, Bp, x, xm1, lane);
}

// ---------------------------------------------------------------------------
// Fused kernel: one block per batch. Waves 1..7 gather/scale rows of
// W (u,v) into a double-buffered LDS ring; wave 0 runs the serial DP.
// ---------------------------------------------------------------------------
__global__ __launch_bounds__(512, 1) void ep_fused_kernel(
    const float* __restrict__ pred, const float* __restrict__ R,
    const float* __restrict__ I, const int* __restrict__ target,
    float* __restrict__ out) {
  const int b    = blockIdx.x;
  const int tid  = threadIdx.x;
  const int lane = tid & 63;
  const int wave = tid >> 6;
  const bool lane0 = (lane == 0);

  // quad layout: buf[buf_idx][row][k*64 + l] = (u[8l+2k], v[8l+2k], u[8l+2k+1], v[8l+2k+1])
  __shared__ float4 buf[2][kCH][kNY / 2];   // 128 KiB
  __shared__ int tgs[kNT];                  // 512 B

  if (tid < kNT) tgs[tid] = target[b * kNT + tid];

  // ---- producer setup (waves 1..7): columns j0 = tid-64, j1 = j0+448 ----
  const int j0 = tid - 64;                       // 0..447 for waves 1..7
  const int j1 = j0 + 448;                       // valid when j0 < 64
  const bool isProd = (wave != 0);
  const bool hasB = isProd && (j1 < kNY);
  float R0a = 0.f, R1a = 0.f, R0b = 0.f, R1b = 0.f;
  const float* pPa = nullptr; const float* pIa = nullptr;
  const float* pPb = nullptr; const float* pIb = nullptr;
  if (isProd) {
    const float* Rb = R + (size_t)b * kNY * 3;
    R0a = Rb[j0 * 3 + 0];
    R1a = (j0 == kNY - 1) ? 1.0f : Rb[j0 * 3 + 1];
    pPa = pred + ((size_t)b * kNY + j0) * kC;
    pIa = I    + ((size_t)b * kNY + j0) * kC;
    if (hasB) {
      R0b = Rb[j1 * 3 + 0];
      R1b = (j1 == kNY - 1) ? 1.0f : Rb[j1 * 3 + 1];
      pPb = pred + ((size_t)b * kNY + j1) * kC;
      pIb = I    + ((size_t)b * kNY + j1) * kC;
    }
  }

  // produce one chunk of W rows into buf[bi]
  auto produce = [&](int chunk, int bi) {
    const int r0   = chunk * kCH;
    const int rows = (kNW - r0 < kCH) ? (kNW - r0) : kCH;
    // column j -> quad k=(j&7)>>1, lane l=j>>3, elem e=j&1
    const int ka = (j0 & 7) >> 1, la = j0 >> 3, ea = j0 & 1;
    const int kb = (j1 & 7) >> 1, lb = j1 >> 3, eb = j1 & 1;
    for (int r = 0; r < rows; ++r) {
      const int t = tgs[r0 + r];
      float2* f2 = (float2*)&buf[bi][r][0];
      {
        const float u = R0a * pPa[t];
        const float v = R1a * pIa[t];
        f2[(ka * 64 + la) * 2 + ea] = make_float2(u, v);
      }
      if (hasB) {
        const float u = R0b * pPb[t];
        const float v = R1b * pIb[t];
        f2[(kb * 64 + lb) * 2 + eb] = make_float2(u, v);
      }
    }
  };

  __syncthreads();          // tgs visible
  if (isProd) produce(0, 0);

  // ---- consumer setup (wave 0), overlapped with produce(0) ----
  float x[8];
  float xm1 = 0.0f;
  float R2m[8], R2o[8];
  unsigned long long eosLo = 0ull, eosHi = 0ull;
  if (wave == 0) {
    const int ta = target[b * kNT + lane];
    const int tb = target[b * kNT + 64 + lane];
    eosLo = __ballot(ta == kEOS);
    eosHi = __ballot(tb == kEOS);

    const float* Rb = R + (size_t)b * kNY * 3;
#pragma unroll
    for (int c = 0; c < 8; ++c) R2o[c] = Rb[(lane * 8 + c) * 3 + 2];
    float r2m0 = 0.0f;
    if (lane != 0) r2m0 = Rb[(lane * 8 - 1) * 3 + 2];  // exec-masked
    R2m[0] = r2m0;
#pragma unroll
    for (int c = 1; c < 8; ++c) R2m[c] = R2o[c - 1];

    // ---- DP row 0: ep[0,0]=1; ep[0,j]=ep[0,j-1]*(eos0 ? 1 : R2[j]) ----
    const bool eos0 = (eosLo & 1ull) != 0ull;
    float A[8], Bv[8], Ap[8], Bp[8];
    A[0]  = lane0 ? 1.0f : 0.0f;
    Bv[0] = lane0 ? 0.0f : (eos0 ? 1.0f : R2o[0]);
#pragma unroll
    for (int c = 1; c < 8; ++c) { A[c] = 0.0f; Bv[c] = eos0 ? 1.0f : R2o[c]; }
    Ap[0] = A[0]; Bp[0] = Bv[0];
#pragma unroll
    for (int c = 1; c < 8; ++c) {
      Ap[c] = fmaf(Bv[c], Ap[c - 1], A[c]);
      Bp[c] = Bv[c] * Bp[c - 1];
    }
    scan_apply(Ap, Bp, x, xm1, lane);
  }

  auto eosAt = [&](int i) -> bool {
    return ((i < 64 ? (eosLo >> i) : (eosHi >> (i - 64))) & 1ull) != 0ull;
  };

  // ---- main loop: consume chunk k while producing chunk k+1 ----
  for (int k = 0; k < kNCH; ++k) {
    __syncthreads();   // chunk k fully in buf[k&1]; buf[(k+1)&1] free
    if (isProd) {
      if (k + 1 < kNCH) produce(k + 1, (k + 1) & 1);
    } else {
      const int r0   = k * kCH;
      const int rows = (kNW - r0 < kCH) ? (kNW - r0) : kCH;
      const float4* rp0 = &buf[k & 1][0][0];
      for (int r = 0; r < rows; ++r) {
        const float4* rp = rp0 + (size_t)r * (kNY / 2);
        const float4 q0 = rp[0 * 64 + lane];
        const float4 q1 = rp[1 * 64 + lane];
        const float4 q2 = rp[2 * 64 + lane];
        const float4 q3 = rp[3 * 64 + lane];
        // W row i = r0 + r feeds DP row (i+1); p_D row index = i+1
        dp_row(q0, q1, q2, q3, eosAt(r0 + r + 1), lane0, R2m, x, xm1, lane);
      }
    }
  }

  if (tid == 63) out[b] = x[7];   // ep[127, 511]
}

}  // namespace

extern "C" void kernel_launch(void* const* d_in, const int* in_sizes, int n_in,
                              void* d_out, int out_size, void* d_ws, size_t ws_size,
                              hipStream_t stream) {
  const float* pred = (const float*)d_in[0];
  const float* R    = (const float*)d_in[1];
  const float* I    = (const float*)d_in[2];
  const int* target = (const int*)d_in[3];
  float* out = (float*)d_out;
  (void)in_sizes; (void)n_in; (void)out_size; (void)d_ws; (void)ws_size;

  ep_fused_kernel<<<dim3(128), dim3(512), 0, stream>>>(pred, R, I, target, out);
}

// Round 6
// 211.458 us; speedup vs baseline: 1.2438x; 1.2438x over previous
//
#include <hip/hip_runtime.h>

namespace {

constexpr int kNY    = 512;
constexpr int kNT    = 128;
constexpr int kC     = 128;
constexpr int kEOS   = 1;
constexpr int kTJ    = 128;           // columns per tile
constexpr int kNTile = kNY / kTJ;     // 4
constexpr int kLP    = 130;           // padded LDS stride (even => 8B-aligned b64 reads)

// ---------------------------------------------------------------------------
// DPP helpers (pure builtins; lane_prev + scan verified on HW in R4).
// ---------------------------------------------------------------------------
template <int CTRL, int RM>
__device__ __forceinline__ float dppf(float src, float old) {
  return __int_as_float(__builtin_amdgcn_update_dpp(
      __float_as_int(old), __float_as_int(src), CTRL, RM, 0xF, false));
}

// value of `v` in lane-1 (lane 0 -> 0.0f)
__device__ __forceinline__ float lane_prev(float v, int lane) {
  float s1  = dppf<0x111, 0xF>(v, 0.0f);   // row_shr:1 (within 16)
  float b15 = dppf<0x142, 0xA>(v, 0.0f);   // lanes 16-31<-15, 48-63<-47
  float b31 = dppf<0x143, 0x4>(v, 0.0f);   // lanes 32-47<-31
  float r = s1;
  r = (lane == 16 || lane == 48) ? b15 : r;
  r = (lane == 32) ? b31 : r;
  return r;
}

// inclusive 64-lane affine scan of per-lane composed transform (SA,SB),
// exclusive carry, apply to the lane's two columns.
__device__ __forceinline__ void scan2(float A0, float B0, float Ap1, float Bp1,
                                      float& x0, float& x1, int lane) {
  float SA = Ap1, SB = Bp1;
#define EP_SCAN_STEP(CTRL, RM)                                   \
  { float a = dppf<CTRL, RM>(SA, 0.0f);                          \
    float bb = dppf<CTRL, RM>(SB, 1.0f);                         \
    SA = fmaf(SB, a, SA); SB *= bb; }
  EP_SCAN_STEP(0x111, 0xF)   // row_shr:1
  EP_SCAN_STEP(0x112, 0xF)   // row_shr:2
  EP_SCAN_STEP(0x114, 0xF)   // row_shr:4
  EP_SCAN_STEP(0x118, 0xF)   // row_shr:8
  EP_SCAN_STEP(0x142, 0xA)   // row_bcast:15 -> rows 1,3
  EP_SCAN_STEP(0x143, 0xC)   // row_bcast:31 -> rows 2,3
#undef EP_SCAN_STEP
  const float carry = lane_prev(SA, lane);   // composition of lanes 0..l-1 @ 0
  x0 = fmaf(B0, carry, A0);
  x1 = fmaf(Bp1, carry, Ap1);
}

// ---------------------------------------------------------------------------
// Fused, column-tiled kernel. One block per batch, 512 threads.
// Per tile: all threads stage u=R0*pred, v=R1'*I transposed into LDS
// (coalesced float4 reads, conflict-free scatter writes), then wave 0 runs
// all 128 DP rows over the tile's 128 columns (2 cols/lane affine scan),
// carrying right-edge boundaries to the next tile through tiny LDS arrays.
// ---------------------------------------------------------------------------
__global__ __launch_bounds__(512, 1) void ep_tiled_kernel(
    const float* __restrict__ pred, const float* __restrict__ R,
    const float* __restrict__ I, const int* __restrict__ target,
    float* __restrict__ out) {
  const int b    = blockIdx.x;
  const int tid  = threadIdx.x;
  const int lane = tid & 63;
  const int wave = tid >> 6;
  const bool lane0 = (lane == 0);

  __shared__ float P[kC * kLP];      // u staged: P[c*kLP + jl]
  __shared__ float Q[kC * kLP];      // v staged
  __shared__ int   tgs[kNT];
  __shared__ float bndE[2][kNT];     // ep[i][tile_right_edge], parity by tile
  __shared__ float bndU[2][kNT];     // u_{i-1}[tile_right_edge]

  if (tid < kNT) tgs[tid] = target[b * kNT + tid];

  // producer mapping: thread -> (column-in-tile jl, class quartet base cq)
  const int jl = tid >> 2;           // 0..127
  const int cq = (tid & 3) * 4;      // classes cq + 16*k + e  (bank-friendly)

  // consumer persistent state (wave 0)
  float x0 = 0.0f, x1 = 0.0f;
  unsigned long long eosLo = 0ull, eosHi = 0ull;
  if (wave == 0) {
    const int ta = target[b * kNT + lane];
    const int tb = target[b * kNT + 64 + lane];
    eosLo = __ballot(ta == kEOS);
    eosHi = __ballot(tb == kEOS);
  }

  // preload tile 0 panel into registers (coalesced)
  float4 pa[8], qa[8];
  {
    const float* Pg = pred + ((size_t)b * kNY + jl) * kC + cq;
    const float* Ig = I    + ((size_t)b * kNY + jl) * kC + cq;
#pragma unroll
    for (int k = 0; k < 8; ++k) {
      pa[k] = *(const float4*)(Pg + k * 16);
      qa[k] = *(const float4*)(Ig + k * 16);
    }
  }

  for (int tile = 0; tile < kNTile; ++tile) {
    const int j0 = tile * kTJ;
    const bool first = (tile == 0);
    __syncthreads();                 // previous tile's DP done; P/Q free

    // ---- stage: fold R factors, transpose into LDS ----
    {
      const int j = j0 + jl;
      const float R0 = R[((size_t)b * kNY + j) * 3 + 0];
      const float R1 = (j == kNY - 1) ? 1.0f : R[((size_t)b * kNY + j) * 3 + 1];
#pragma unroll
      for (int k = 0; k < 8; ++k) {
        const int c = cq + 16 * k;
        P[(c + 0) * kLP + jl] = R0 * pa[k].x;
        P[(c + 1) * kLP + jl] = R0 * pa[k].y;
        P[(c + 2) * kLP + jl] = R0 * pa[k].z;
        P[(c + 3) * kLP + jl] = R0 * pa[k].w;
        Q[(c + 0) * kLP + jl] = R1 * qa[k].x;
        Q[(c + 1) * kLP + jl] = R1 * qa[k].y;
        Q[(c + 2) * kLP + jl] = R1 * qa[k].z;
        Q[(c + 3) * kLP + jl] = R1 * qa[k].w;
      }
    }
    // ---- prefetch next tile's panel into registers (hides HBM under DP) ----
    if (tile + 1 < kNTile) {
      const int jn = (tile + 1) * kTJ + jl;
      const float* Pg = pred + ((size_t)b * kNY + jn) * kC + cq;
      const float* Ig = I    + ((size_t)b * kNY + jn) * kC + cq;
#pragma unroll
      for (int k = 0; k < 8; ++k) {
        pa[k] = *(const float4*)(Pg + k * 16);
        qa[k] = *(const float4*)(Ig + k * 16);
      }
    }
    __syncthreads();                 // tile staged

    // ---- consumer: wave 0 runs DP rows 0..127 over this tile ----
    if (wave == 0) {
      const int wp = tile & 1;         // write parity
      const int rp = wp ^ 1;           // read parity (prev tile's edges)
      const float* bE_r = bndE[rp];
      const float* bU_r = bndU[rp];
      float* bE_w = bndE[wp];
      float* bU_w = bndU[wp];

      const int ja = j0 + 2 * lane;    // lane's first column
      const int jb = ja + 1;           // lane's second column
      const float* Rb = R + (size_t)b * kNY * 3;
      const float R2o0 = Rb[ja * 3 + 2];       // R2[ja]
      const float R2o1 = Rb[jb * 3 + 2];       // R2[jb]
      float R2m0 = 0.0f;
      if (ja >= 1) R2m0 = Rb[(ja - 1) * 3 + 2];  // R2[ja-1], exec-masked

      // ---- row 0: ep[0][j] = ep[0][j-1] * (eos0 ? 1 : R2[j]) ----
      const bool eos0 = (eosLo & 1ull) != 0ull;
      {
        float B0 = eos0 ? 1.0f : R2o0;
        float B1 = eos0 ? 1.0f : R2o1;
        float A0 = 0.0f;
        if (lane0) {
          if (first) { A0 = 1.0f; B0 = 0.0f; }       // ep[0][0] = 1
          else       { A0 = B0 * bE_r[0]; }          // fold carry ep[0][j0-1]
        }
        const float Ap1 = B1 * A0;
        const float Bp1 = B1 * B0;
        scan2(A0, B0, Ap1, Bp1, x0, x1, lane);
        if (lane == 63) bE_w[0] = x1;
      }
      float bE_prev = bE_r[0];   // ep[i-1][j0-1] rolling (garbage on tile 0; unused)

      // ---- rows 1..127 ----
      float2 U = *(const float2*)&P[tgs[0] * kLP + 2 * lane];
      float2 V = *(const float2*)&Q[tgs[0] * kLP + 2 * lane];
      for (int i = 1; i < kNT; ++i) {
        // prefetch next row's u,v (i=127 read is harmless, in-bounds)
        const int tn = tgs[i];
        float2 Un = *(const float2*)&P[tn * kLP + 2 * lane];
        float2 Vn = *(const float2*)&Q[tn * kLP + 2 * lane];

        const float bE_cur = bE_r[i];   // ep[i][j0-1] (prev tile edge)
        const float bU_cur = bU_r[i];   // u_{i-1}[j0-1]
        const bool eos =
            ((i < 64 ? (eosLo >> i) : (eosHi >> (i - 64))) & 1ull) != 0ull;
        float B0 = eos ? 1.0f : R2m0;          // p_D[i][ja-1]
        const float B1 = eos ? 1.0f : R2o0;    // p_D[i][jb-1] = R2[ja]

        // pm1 = ep[i-1][ja-1] * u_{i-1}[ja-1]
        float pm1 = lane_prev(x1 * U.y, lane);
        if (lane0 && !first) pm1 = bE_prev * bU_cur;
        float A0 = fmaf(x0, V.x, pm1);
        if (lane0) {
          if (first) { A0 = x0 * V.y; B0 = 0.0f; }   // ep[i][0] = ep[i-1][0]*v[1]
          else       { A0 = fmaf(B0, bE_cur, A0); }  // fold carry ep[i][j0-1]
        }
        const float A1  = fmaf(x1, V.y, x0 * U.x);
        const float Ap1 = fmaf(B1, A0, A1);
        const float Bp1 = B1 * B0;
        scan2(A0, B0, Ap1, Bp1, x0, x1, lane);
        if (lane == 63) { bE_w[i] = x1; bU_w[i] = U.y; }
        bE_prev = bE_cur;
        U = Un; V = Vn;
      }
    }
  }

  if (tid == 63) out[b] = x1;   // wave 0, lane 63: ep[127][511]
}

}  // namespace

extern "C" void kernel_launch(void* const* d_in, const int* in_sizes, int n_in,
                              void* d_out, int out_size, void* d_ws, size_t ws_size,
                              hipStream_t stream) {
  const float* pred = (const float*)d_in[0];
  const float* R    = (const float*)d_in[1];
  const float* I    = (const float*)d_in[2];
  const int* target = (const int*)d_in[3];
  float* out = (float*)d_out;
  (void)in_sizes; (void)n_in; (void)out_size; (void)d_ws; (void)ws_size;

  ep_tiled_kernel<<<dim3(128), dim3(512), 0, stream>>>(pred, R, I, target, out);
}

// Round 7
// 204.012 us; speedup vs baseline: 1.2892x; 1.0365x over previous
//
#include <hip/hip_runtime.h>
#include <type_traits>

namespace {

constexpr int kNY    = 512;
constexpr int kNT    = 128;
constexpr int kC     = 128;
constexpr int kEOS   = 1;
constexpr int kTJ    = 128;           // columns per tile
constexpr int kNTile = kNY / kTJ;     // 4
constexpr int kLP    = 130;           // padded LDS stride (even => 8B-aligned b64 reads)

// ---------------------------------------------------------------------------
// DPP helpers (pure builtins; lane_prev + scan verified on HW: absmax 0.0).
// ---------------------------------------------------------------------------
template <int CTRL, int RM>
__device__ __forceinline__ float dppf(float src, float old) {
  return __int_as_float(__builtin_amdgcn_update_dpp(
      __float_as_int(old), __float_as_int(src), CTRL, RM, 0xF, false));
}

// value of `v` in lane-1 (lane 0 -> 0.0f)
__device__ __forceinline__ float lane_prev(float v, int lane) {
  float s1  = dppf<0x111, 0xF>(v, 0.0f);   // row_shr:1 (within 16)
  float b15 = dppf<0x142, 0xA>(v, 0.0f);   // lanes 16-31<-15, 48-63<-47
  float b31 = dppf<0x143, 0x4>(v, 0.0f);   // lanes 32-47<-31
  float r = s1;
  r = (lane == 16 || lane == 48) ? b15 : r;
  r = (lane == 32) ? b31 : r;
  return r;
}

// inclusive 64-lane affine scan of per-lane composed transform (SA,SB),
// exclusive carry, apply to the lane's two columns.
__device__ __forceinline__ void scan2(float A0, float B0, float Ap1, float Bp1,
                                      float& x0, float& x1, int lane) {
  float SA = Ap1, SB = Bp1;
#define EP_SCAN_STEP(CTRL, RM)                                   \
  { float a = dppf<CTRL, RM>(SA, 0.0f);                          \
    float bb = dppf<CTRL, RM>(SB, 1.0f);                         \
    SA = fmaf(SB, a, SA); SB *= bb; }
  EP_SCAN_STEP(0x111, 0xF)   // row_shr:1
  EP_SCAN_STEP(0x112, 0xF)   // row_shr:2
  EP_SCAN_STEP(0x114, 0xF)   // row_shr:4
  EP_SCAN_STEP(0x118, 0xF)   // row_shr:8
  EP_SCAN_STEP(0x142, 0xA)   // row_bcast:15 -> rows 1,3
  EP_SCAN_STEP(0x143, 0xC)   // row_bcast:31 -> rows 2,3
#undef EP_SCAN_STEP
  const float carry = lane_prev(SA, lane);   // composition of lanes 0..l-1 @ 0
  x0 = fmaf(B0, carry, A0);
  x1 = fmaf(Bp1, carry, Ap1);
}

// ---------------------------------------------------------------------------
// Fused, column-tiled kernel. One block per batch, 512 threads.
// Per tile: all threads stage u=R0*pred, v=R1'*I transposed into LDS
// (coalesced float4 reads, conflict-free scatter writes), then wave 0 runs
// all 128 DP rows over the tile's 128 columns (2 cols/lane affine scan).
// R7: row loop fully software-pipelined — every LDS value consumed at row i
// (U/V, boundary values, next target index) is issued at row i-1; eos test
// is a rolling mask; the tile-0 branch is a compile-time specialization.
// ---------------------------------------------------------------------------
__global__ __launch_bounds__(512, 1) void ep_tiled_kernel(
    const float* __restrict__ pred, const float* __restrict__ R,
    const float* __restrict__ I, const int* __restrict__ target,
    float* __restrict__ out) {
  const int b    = blockIdx.x;
  const int tid  = threadIdx.x;
  const int lane = tid & 63;
  const int wave = tid >> 6;
  const bool lane0 = (lane == 0);

  __shared__ float P[kC * kLP];      // u staged: P[c*kLP + jl]
  __shared__ float Q[kC * kLP];      // v staged
  __shared__ int   tgs[kNT];
  __shared__ float bndE[2][kNT];     // ep[i][tile_right_edge], parity by tile
  __shared__ float bndU[2][kNT];     // u_{i-1}[tile_right_edge]

  if (tid < kNT) tgs[tid] = target[b * kNT + tid];

  // producer mapping: thread -> (column-in-tile jl, class quartet base cq)
  const int jl = tid >> 2;           // 0..127
  const int cq = (tid & 3) * 4;      // classes cq + 16*k + e  (bank-friendly)

  // consumer persistent state (wave 0)
  float x0 = 0.0f, x1 = 0.0f;
  unsigned long long eosLo = 0ull, eosHi = 0ull;
  if (wave == 0) {
    const int ta = target[b * kNT + lane];
    const int tb = target[b * kNT + 64 + lane];
    eosLo = __ballot(ta == kEOS);
    eosHi = __ballot(tb == kEOS);
  }

  // preload tile 0 panel into registers (coalesced)
  float4 pa[8], qa[8];
  {
    const float* Pg = pred + ((size_t)b * kNY + jl) * kC + cq;
    const float* Ig = I    + ((size_t)b * kNY + jl) * kC + cq;
#pragma unroll
    for (int k = 0; k < 8; ++k) {
      pa[k] = *(const float4*)(Pg + k * 16);
      qa[k] = *(const float4*)(Ig + k * 16);
    }
  }

  for (int tile = 0; tile < kNTile; ++tile) {
    const int j0 = tile * kTJ;
    __syncthreads();                 // previous tile's DP done; P/Q free

    // ---- stage: fold R factors, transpose into LDS ----
    {
      const int j = j0 + jl;
      const float R0 = R[((size_t)b * kNY + j) * 3 + 0];
      const float R1 = (j == kNY - 1) ? 1.0f : R[((size_t)b * kNY + j) * 3 + 1];
#pragma unroll
      for (int k = 0; k < 8; ++k) {
        const int c = cq + 16 * k;
        P[(c + 0) * kLP + jl] = R0 * pa[k].x;
        P[(c + 1) * kLP + jl] = R0 * pa[k].y;
        P[(c + 2) * kLP + jl] = R0 * pa[k].z;
        P[(c + 3) * kLP + jl] = R0 * pa[k].w;
        Q[(c + 0) * kLP + jl] = R1 * qa[k].x;
        Q[(c + 1) * kLP + jl] = R1 * qa[k].y;
        Q[(c + 2) * kLP + jl] = R1 * qa[k].z;
        Q[(c + 3) * kLP + jl] = R1 * qa[k].w;
      }
    }
    // ---- prefetch next tile's panel into registers (hides HBM under DP) ----
    if (tile + 1 < kNTile) {
      const int jn = (tile + 1) * kTJ + jl;
      const float* Pg = pred + ((size_t)b * kNY + jn) * kC + cq;
      const float* Ig = I    + ((size_t)b * kNY + jn) * kC + cq;
#pragma unroll
      for (int k = 0; k < 8; ++k) {
        pa[k] = *(const float4*)(Pg + k * 16);
        qa[k] = *(const float4*)(Ig + k * 16);
      }
    }
    __syncthreads();                 // tile staged

    // ---- consumer: wave 0 runs DP rows 0..127 over this tile ----
    if (wave == 0) {
      auto run_tile = [&](auto firstc) {
        constexpr bool FIRSTC = decltype(firstc)::value;
        const int wp = tile & 1;         // write parity
        const int rp = wp ^ 1;           // read parity (prev tile's edges)
        const float* bE_r = bndE[rp];
        const float* bU_r = bndU[rp];
        float* bE_w = bndE[wp];
        float* bU_w = bndU[wp];

        const int ja = j0 + 2 * lane;    // lane's first column
        const float* Rb = R + (size_t)b * kNY * 3;
        const float R2o0 = Rb[ja * 3 + 2];       // R2[ja]
        const float R2o1 = Rb[ja * 3 + 5];       // R2[ja+1]
        float R2m0 = 0.0f;
        if (ja >= 1) R2m0 = Rb[ja * 3 - 1];      // R2[ja-1], exec-masked

        // ---- row 0: ep[0][j] = ep[0][j-1] * (eos0 ? 1 : R2[j]) ----
        const bool eos0 = (eosLo & 1ull) != 0ull;
        {
          float B0 = eos0 ? 1.0f : R2o0;
          const float B1 = eos0 ? 1.0f : R2o1;
          float A0 = 0.0f;
          if (lane0) {
            if (FIRSTC) { A0 = 1.0f; B0 = 0.0f; }      // ep[0][0] = 1
            else        { A0 = B0 * bE_r[0]; }         // fold ep[0][j0-1]
          }
          const float Ap1 = B1 * A0;
          const float Bp1 = B1 * B0;
          scan2(A0, B0, Ap1, Bp1, x0, x1, lane);
          if (lane == 63) bE_w[0] = x1;
        }

        // ---- software-pipeline prologue for row 1 ----
        float2 U = *(const float2*)&P[tgs[0] * kLP + 2 * lane];
        float2 V = *(const float2*)&Q[tgs[0] * kLP + 2 * lane];
        int tA = tgs[1];                         // target row 1 (for row 2's U/V)
        float bE_prev = FIRSTC ? 0.0f : bE_r[0]; // ep[i-1][j0-1]
        float bE_cur  = FIRSTC ? 0.0f : bE_r[1]; // ep[i][j0-1]
        float bU_cur  = FIRSTC ? 0.0f : bU_r[1]; // u_{i-1}[j0-1]
        unsigned long long m = eosLo >> 1;       // bit0 = eos(row 1)

        // ---- rows 1..127 ----
        for (int i = 1; i < kNT; ++i) {
          // prefetch everything row i+1 needs (issued before compute)
          const int ip = (i < kNT - 1) ? (i + 1) : (kNT - 1);
          const float2 Un = *(const float2*)&P[tA * kLP + 2 * lane];
          const float2 Vn = *(const float2*)&Q[tA * kLP + 2 * lane];
          const int tB = tgs[ip];
          const float bE_n = FIRSTC ? 0.0f : bE_r[ip];
          const float bU_n = FIRSTC ? 0.0f : bU_r[ip];

          const bool eos = (m & 1ull) != 0ull;
          float B0 = eos ? 1.0f : R2m0;          // p_D[i][ja-1]
          const float B1 = eos ? 1.0f : R2o0;    // p_D[i][jb-1] = R2[ja]

          // pm1 = ep[i-1][ja-1] * u_{i-1}[ja-1]
          float pm1 = lane_prev(x1 * U.y, lane);
          if (lane0 && !FIRSTC) pm1 = bE_prev * bU_cur;
          float A0 = fmaf(x0, V.x, pm1);
          if (lane0) {
            if (FIRSTC) { A0 = x0 * V.y; B0 = 0.0f; }   // ep[i][0]=ep[i-1][0]*v[1]
            else        { A0 = fmaf(B0, bE_cur, A0); }  // fold ep[i][j0-1]
          }
          const float A1  = fmaf(x1, V.y, x0 * U.x);
          const float Ap1 = fmaf(B1, A0, A1);
          const float Bp1 = B1 * B0;
          scan2(A0, B0, Ap1, Bp1, x0, x1, lane);
          if (lane == 63) { bE_w[i] = x1; bU_w[i] = U.y; }

          // rotate pipeline registers
          bE_prev = bE_cur; bE_cur = bE_n; bU_cur = bU_n;
          U = Un; V = Vn; tA = tB;
          if (i == 63) m = eosHi; else m >>= 1;   // bit0 = eos(row i+1)
        }
      };
      if (tile == 0) run_tile(std::integral_constant<bool, true>{});
      else           run_tile(std::integral_constant<bool, false>{});
    }
  }

  if (tid == 63) out[b] = x1;   // wave 0, lane 63: ep[127][511]
}

}  // namespace

extern "C" void kernel_launch(void* const* d_in, const int* in_sizes, int n_in,
                              void* d_out, int out_size, void* d_ws, size_t ws_size,
                              hipStream_t stream) {
  const float* pred = (const float*)d_in[0];
  const float* R    = (const float*)d_in[1];
  const float* I    = (const float*)d_in[2];
  const int* target = (const int*)d_in[3];
  float* out = (float*)d_out;
  (void)in_sizes; (void)n_in; (void)out_size; (void)d_ws; (void)ws_size;

  ep_tiled_kernel<<<dim3(128), dim3(512), 0, stream>>>(pred, R, I, target, out);
}

// Round 8
// 140.416 us; speedup vs baseline: 1.8732x; 1.4529x over previous
//
#include <hip/hip_runtime.h>
#include <type_traits>

namespace {

constexpr int kNY    = 512;
constexpr int kNT    = 128;
constexpr int kC     = 128;
constexpr int kEOS   = 1;
constexpr int kB     = 128;
constexpr int kTJ    = 128;           // columns per tile (fused path)
constexpr int kNTile = kNY / kTJ;     // 4
constexpr int kLP    = 130;           // padded LDS stride
constexpr int kJT    = 64;            // j-tile width (gather kernel)
constexpr int kLPg   = 65;            // padded stride (gather kernel)

// ---------------------------------------------------------------------------
// DPP helpers (pure builtins; HW-verified absmax 0.0 in R4/R6/R7).
// ---------------------------------------------------------------------------
template <int CTRL, int RM>
__device__ __forceinline__ float dppf(float src, float old) {
  return __int_as_float(__builtin_amdgcn_update_dpp(
      __float_as_int(old), __float_as_int(src), CTRL, RM, 0xF, false));
}

// value of `v` in lane-1 (lane 0 -> 0.0f)
__device__ __forceinline__ float lane_prev(float v, int lane) {
  float s1  = dppf<0x111, 0xF>(v, 0.0f);   // row_shr:1 (within 16)
  float b15 = dppf<0x142, 0xA>(v, 0.0f);   // lanes 16-31<-15, 48-63<-47
  float b31 = dppf<0x143, 0x4>(v, 0.0f);   // lanes 32-47<-31
  float r = s1;
  r = (lane == 16 || lane == 48) ? b15 : r;
  r = (lane == 32) ? b31 : r;
  return r;
}

#define EP_SCAN_6STEPS                                           \
  EP_SCAN_STEP(0x111, 0xF)                                       \
  EP_SCAN_STEP(0x112, 0xF)                                       \
  EP_SCAN_STEP(0x114, 0xF)                                       \
  EP_SCAN_STEP(0x118, 0xF)                                       \
  EP_SCAN_STEP(0x142, 0xA)                                       \
  EP_SCAN_STEP(0x143, 0xC)

// 2-col variant (fused kernel)
__device__ __forceinline__ void scan2(float A0, float B0, float Ap1, float Bp1,
                                      float& x0, float& x1, int lane) {
  float SA = Ap1, SB = Bp1;
#define EP_SCAN_STEP(CTRL, RM)                                   \
  { float a = dppf<CTRL, RM>(SA, 0.0f);                          \
    float bb = dppf<CTRL, RM>(SB, 1.0f);                         \
    SA = fmaf(SB, a, SA); SB *= bb; }
  EP_SCAN_6STEPS
#undef EP_SCAN_STEP
  const float carry = lane_prev(SA, lane);
  x0 = fmaf(B0, carry, A0);
  x1 = fmaf(Bp1, carry, Ap1);
}

// 8-col variant (dp kernel): inclusive scan of composed (Ap[7],Bp[7]),
// exclusive carry, apply to all 8 columns.
__device__ __forceinline__ void scan_apply8(const float (&Ap)[8],
                                            const float (&Bp)[8],
                                            float (&x)[8], float& xm1,
                                            int lane) {
  float SA = Ap[7], SB = Bp[7];
#define EP_SCAN_STEP(CTRL, RM)                                   \
  { float a = dppf<CTRL, RM>(SA, 0.0f);                          \
    float bb = dppf<CTRL, RM>(SB, 1.0f);                         \
    SA = fmaf(SB, a, SA); SB *= bb; }
  EP_SCAN_6STEPS
#undef EP_SCAN_STEP
  const float carry = lane_prev(SA, lane);
#pragma unroll
  for (int c = 0; c < 8; ++c) x[c] = fmaf(Bp[c], carry, Ap[c]);
  xm1 = carry;
}

// ===========================================================================
// PATH A (ws_size >= 64 MiB): gather kernel + 8-col dp kernel (plain C++).
// ===========================================================================
__global__ __launch_bounds__(256, 1) void gather_kernel(
    const float* __restrict__ pred, const float* __restrict__ R,
    const float* __restrict__ I, const int* __restrict__ target,
    float2* __restrict__ W) {
  const int jt = blockIdx.x;        // 0..7
  const int b  = blockIdx.y;        // 0..127
  const int j0 = jt * kJT;
  const int tid = threadIdx.x;

  __shared__ float P[kC * kLPg];
  __shared__ float Q[kC * kLPg];
  __shared__ int tgs[kNT];

  if (tid < kNT) tgs[tid] = target[b * kNT + tid];

  {
    const int cg = (tid & 31) * 4;   // class offset 0..124
    int jl = tid >> 5;               // 0..7, step 8
    const float* Pb = pred + ((size_t)b * kNY + j0) * kC;
    const float* Ib = I    + ((size_t)b * kNY + j0) * kC;
#pragma unroll
    for (int it = 0; it < 8; ++it, jl += 8) {
      float4 a = *(const float4*)(Pb + (size_t)jl * kC + cg);
      float4 e = *(const float4*)(Ib + (size_t)jl * kC + cg);
      P[(cg + 0) * kLPg + jl] = a.x;  P[(cg + 1) * kLPg + jl] = a.y;
      P[(cg + 2) * kLPg + jl] = a.z;  P[(cg + 3) * kLPg + jl] = a.w;
      Q[(cg + 0) * kLPg + jl] = e.x;  Q[(cg + 1) * kLPg + jl] = e.y;
      Q[(cg + 2) * kLPg + jl] = e.z;  Q[(cg + 3) * kLPg + jl] = e.w;
    }
  }
  const int l = tid & 63;            // lane
  const int w = tid >> 6;            // wave 0..3
  const int j = j0 + l;
  const float R0l = R[((size_t)b * kNY + j) * 3 + 0];
  const float R1l = (j == kNY - 1) ? 1.0f : R[((size_t)b * kNY + j) * 3 + 1];
  __syncthreads();

#pragma unroll 4
  for (int p = 0; p < 32; ++p) {
    const int i = p * 4 + w;
    const int t = tgs[i];
    float u = R0l * P[t * kLPg + l];
    float v = R1l * Q[t * kLPg + l];
    W[((size_t)b * kNT + i) * kNY + j] = make_float2(u, v);
  }
}

// One DP row, 8 cols/lane; quads are (u,v,u,v) pairs (HW-verified math).
__device__ __forceinline__ void dp_row8(const float4& q0, const float4& q1,
                                        const float4& q2, const float4& q3,
                                        bool eos, bool lane0,
                                        const float (&R2m)[8], float (&x)[8],
                                        float& xm1, int lane) {
  float u[8], v[8];
  u[0] = q0.x; v[0] = q0.y; u[1] = q0.z; v[1] = q0.w;
  u[2] = q1.x; v[2] = q1.y; u[3] = q1.z; v[3] = q1.w;
  u[4] = q2.x; v[4] = q2.y; u[5] = q2.z; v[5] = q2.w;
  u[6] = q3.x; v[6] = q3.y; u[7] = q3.z; v[7] = q3.w;

  float A[8], Bv[8], Ap[8], Bp[8];
  const float um1 = lane_prev(u[7], lane);
  A[0]  = lane0 ? x[0] * v[1] : fmaf(x[0], v[0], xm1 * um1);
  Bv[0] = lane0 ? 0.0f : (eos ? 1.0f : R2m[0]);
#pragma unroll
  for (int c = 1; c < 8; ++c) {
    A[c]  = fmaf(x[c], v[c], x[c - 1] * u[c - 1]);
    Bv[c] = eos ? 1.0f : R2m[c];
  }
  Ap[0] = A[0]; Bp[0] = Bv[0];
#pragma unroll
  for (int c = 1; c < 8; ++c) {
    Ap[c] = fmaf(Bv[c], Ap[c - 1], A[c]);
    Bp[c] = Bv[c] * Bp[c - 1];
  }
  scan_apply8(Ap, Bp, x, xm1, lane);
}

__global__ __launch_bounds__(64, 1) void dp_kernel(
    const float2* __restrict__ W, const float* __restrict__ R,
    const int* __restrict__ target, float* __restrict__ out) {
  const int b = blockIdx.x;
  const int lane = threadIdx.x;
  const bool lane0 = (lane == 0);

  const int ta = target[b * kNT + lane];
  const int tb = target[b * kNT + 64 + lane];
  const unsigned long long eosLo = __ballot(ta == kEOS);
  const unsigned long long eosHi = __ballot(tb == kEOS);

  const float* Rb = R + (size_t)b * kNY * 3;
  float R2m[8], R2o[8];
#pragma unroll
  for (int c = 0; c < 8; ++c) R2o[c] = Rb[(lane * 8 + c) * 3 + 2];
  float r2m0 = 0.0f;
  if (lane != 0) r2m0 = Rb[(lane * 8 - 1) * 3 + 2];   // exec-masked
  R2m[0] = r2m0;
#pragma unroll
  for (int c = 1; c < 8; ++c) R2m[c] = R2o[c - 1];

  float x[8];
  float xm1 = 0.0f;

  // ---- row 0 ----
  {
    const bool eos0 = (eosLo & 1ull) != 0ull;
    float A[8], Bv[8], Ap[8], Bp[8];
    A[0]  = lane0 ? 1.0f : 0.0f;
    Bv[0] = lane0 ? 0.0f : (eos0 ? 1.0f : R2o[0]);
#pragma unroll
    for (int c = 1; c < 8; ++c) { A[c] = 0.0f; Bv[c] = eos0 ? 1.0f : R2o[c]; }
    Ap[0] = A[0]; Bp[0] = Bv[0];
#pragma unroll
    for (int c = 1; c < 8; ++c) {
      Ap[c] = fmaf(Bv[c], Ap[c - 1], A[c]);
      Bp[c] = Bv[c] * Bp[c - 1];
    }
    scan_apply8(Ap, Bp, x, xm1, lane);
  }

  auto eosAt = [&](int i) -> bool {
    return ((i < 64 ? (eosLo >> i) : (eosHi >> (i - 64))) & 1ull) != 0ull;
  };

  const float* Wl = (const float*)(W + (size_t)b * kNT * kNY + lane * 8);
  // depth-4 plain-C++ ring; loads for row r+4 issued BEFORE row r's compute.
  float4 ring[4][4];
#pragma unroll
  for (int r = 0; r < 4; ++r) {
    const float* p = Wl + (size_t)r * (kNY * 2);
    ring[r][0] = *(const float4*)(p + 0);  ring[r][1] = *(const float4*)(p + 4);
    ring[r][2] = *(const float4*)(p + 8);  ring[r][3] = *(const float4*)(p + 12);
  }

  auto step = [&](int r, float4 (&fr)[4]) {
    const float4 c0 = fr[0], c1 = fr[1], c2 = fr[2], c3 = fr[3];
    int nr = r + 4; if (nr > 126) nr = 126;
    const float* np = Wl + (size_t)nr * (kNY * 2);
    fr[0] = *(const float4*)(np + 0);  fr[1] = *(const float4*)(np + 4);
    fr[2] = *(const float4*)(np + 8);  fr[3] = *(const float4*)(np + 12);
    dp_row8(c0, c1, c2, c3, eosAt(r + 1), lane0, R2m, x, xm1, lane);
  };

  for (int g = 0; g < 31; ++g) {     // rows 0..123
#pragma unroll
    for (int rr = 0; rr < 4; ++rr) step(g * 4 + rr, ring[rr]);
  }
#pragma unroll
  for (int rr = 0; rr < 3; ++rr) step(124 + rr, ring[rr]);  // rows 124..126

  if (lane == 63) out[b] = x[7];
}

// ===========================================================================
// PATH B (fallback): fused column-tiled kernel, ground row-step.
// R8: tgs LDS array deleted (targets via uniform readlane from the ballot
// registers), loop split at i=63 (rolling eos mask), branchless lane-0
// folds (no exec toggles on the critical path).
// ===========================================================================
__global__ __launch_bounds__(512, 1) void ep_tiled_kernel(
    const float* __restrict__ pred, const float* __restrict__ R,
    const float* __restrict__ I, const int* __restrict__ target,
    float* __restrict__ out) {
  const int b    = blockIdx.x;
  const int tid  = threadIdx.x;
  const int lane = tid & 63;
  const int wave = tid >> 6;
  const bool lane0 = (lane == 0);

  __shared__ float P[kC * kLP];      // u staged: P[c*kLP + jl]
  __shared__ float Q[kC * kLP];      // v staged
  __shared__ float bndE[2][kNT];     // ep[i][tile_right_edge], parity by tile
  __shared__ float bndU[2][kNT];     // u_{i-1}[tile_right_edge]

  // producer mapping
  const int jl = tid >> 2;           // 0..127
  const int cq = (tid & 3) * 4;

  // consumer persistent state (wave 0)
  float x0 = 0.0f, x1 = 0.0f;
  int ta = 0, tb = 0;
  unsigned long long eosLo = 0ull, eosHi = 0ull;
  if (wave == 0) {
    ta = target[b * kNT + lane];
    tb = target[b * kNT + 64 + lane];
    eosLo = __ballot(ta == kEOS);
    eosHi = __ballot(tb == kEOS);
  }

  // preload tile 0 panel into registers (coalesced)
  float4 pa[8], qa[8];
  {
    const float* Pg = pred + ((size_t)b * kNY + jl) * kC + cq;
    const float* Ig = I    + ((size_t)b * kNY + jl) * kC + cq;
#pragma unroll
    for (int k = 0; k < 8; ++k) {
      pa[k] = *(const float4*)(Pg + k * 16);
      qa[k] = *(const float4*)(Ig + k * 16);
    }
  }

  for (int tile = 0; tile < kNTile; ++tile) {
    const int j0 = tile * kTJ;
    __syncthreads();                 // previous tile's DP done; P/Q free

    // ---- stage: fold R factors, transpose into LDS ----
    {
      const int j = j0 + jl;
      const float R0 = R[((size_t)b * kNY + j) * 3 + 0];
      const float R1 = (j == kNY - 1) ? 1.0f : R[((size_t)b * kNY + j) * 3 + 1];
#pragma unroll
      for (int k = 0; k < 8; ++k) {
        const int c = cq + 16 * k;
        P[(c + 0) * kLP + jl] = R0 * pa[k].x;
        P[(c + 1) * kLP + jl] = R0 * pa[k].y;
        P[(c + 2) * kLP + jl] = R0 * pa[k].z;
        P[(c + 3) * kLP + jl] = R0 * pa[k].w;
        Q[(c + 0) * kLP + jl] = R1 * qa[k].x;
        Q[(c + 1) * kLP + jl] = R1 * qa[k].y;
        Q[(c + 2) * kLP + jl] = R1 * qa[k].z;
        Q[(c + 3) * kLP + jl] = R1 * qa[k].w;
      }
    }
    if (tile + 1 < kNTile) {
      const int jn = (tile + 1) * kTJ + jl;
      const float* Pg = pred + ((size_t)b * kNY + jn) * kC + cq;
      const float* Ig = I    + ((size_t)b * kNY + jn) * kC + cq;
#pragma unroll
      for (int k = 0; k < 8; ++k) {
        pa[k] = *(const float4*)(Pg + k * 16);
        qa[k] = *(const float4*)(Ig + k * 16);
      }
    }
    __syncthreads();                 // tile staged

    if (wave == 0) {
      auto run_tile = [&](auto firstc) {
        constexpr bool FIRSTC = decltype(firstc)::value;
        const int wp = tile & 1;
        const int rp = wp ^ 1;
        const float* bE_r = bndE[rp];
        const float* bU_r = bndU[rp];
        float* bE_w = bndE[wp];
        float* bU_w = bndU[wp];

        const int ja = j0 + 2 * lane;
        const float* Rb = R + (size_t)b * kNY * 3;
        const float R2o0 = Rb[ja * 3 + 2];       // R2[ja]
        const float R2o1 = Rb[ja * 3 + 5];       // R2[ja+1]
        float R2m0 = 0.0f;
        if (ja >= 1) R2m0 = Rb[ja * 3 - 1];      // R2[ja-1], exec-masked

        // ---- row 0 ----
        const bool eos0 = (eosLo & 1ull) != 0ull;
        {
          float B0 = eos0 ? 1.0f : R2o0;
          const float B1 = eos0 ? 1.0f : R2o1;
          float A0 = 0.0f;
          if (FIRSTC) {
            A0 = lane0 ? 1.0f : 0.0f;
            B0 = lane0 ? 0.0f : B0;
          } else {
            A0 = lane0 ? B0 * bE_r[0] : 0.0f;
          }
          const float Ap1 = B1 * A0;
          const float Bp1 = B1 * B0;
          scan2(A0, B0, Ap1, Bp1, x0, x1, lane);
          if (lane == 63) bE_w[0] = x1;
        }

        // ---- pipeline prologue for row 1 ----
        const int t0 = __builtin_amdgcn_readlane(ta, 0);
        float2 U = *(const float2*)&P[t0 * kLP + 2 * lane];
        float2 V = *(const float2*)&Q[t0 * kLP + 2 * lane];
        float bE_prev = FIRSTC ? 0.0f : bE_r[0];
        float bE_cur  = FIRSTC ? 0.0f : bE_r[1];
        float bU_cur  = FIRSTC ? 0.0f : bU_r[1];
        unsigned long long m = eosLo >> 1;       // bit0 = eos(row 1)

        auto row_body = [&](int i, int tn) {
          // prefetch row i+1's operands (tn = t_i, uniform)
          const float2 Un = *(const float2*)&P[tn * kLP + 2 * lane];
          const float2 Vn = *(const float2*)&Q[tn * kLP + 2 * lane];
          const int ip = (i < kNT - 1) ? (i + 1) : (kNT - 1);
          const float bE_n = FIRSTC ? 0.0f : bE_r[ip];
          const float bU_n = FIRSTC ? 0.0f : bU_r[ip];

          const bool eos = (m & 1ull) != 0ull;
          const float B1 = eos ? 1.0f : R2o0;
          float B0 = eos ? 1.0f : R2m0;

          float A0;
          if (FIRSTC) {
            const float pm1 = lane_prev(x1 * U.y, lane);   // 0 at lane0
            const float Vsel = lane0 ? V.y : V.x;
            A0 = fmaf(x0, Vsel, pm1);                      // lane0: x0*v[1]
            B0 = lane0 ? 0.0f : B0;
          } else {
            const float pm1g = lane_prev(x1 * U.y, lane);
            const float pm1  = lane0 ? bE_prev * bU_cur : pm1g;
            A0 = fmaf(x0, V.x, pm1);
            const float A0f = fmaf(B0, bE_cur, A0);        // fold left edge
            A0 = lane0 ? A0f : A0;                         // lane0 B0 benign
          }
          const float A1  = fmaf(x1, V.y, x0 * U.x);
          const float Ap1 = fmaf(B1, A0, A1);
          const float Bp1 = B1 * B0;
          scan2(A0, B0, Ap1, Bp1, x0, x1, lane);
          if (lane == 63) { bE_w[i] = x1; bU_w[i] = U.y; }
          bE_prev = bE_cur; bE_cur = bE_n; bU_cur = bU_n;
          U = Un; V = Vn;
        };

#pragma unroll 2
        for (int i = 1; i < 64; ++i) {
          row_body(i, __builtin_amdgcn_readlane(ta, i));
          m = (i == 63) ? eosHi : (m >> 1);
        }
#pragma unroll 2
        for (int i = 64; i < kNT; ++i) {
          row_body(i, __builtin_amdgcn_readlane(tb, i - 64));
          m >>= 1;
        }
      };
      if (tile == 0) run_tile(std::integral_constant<bool, true>{});
      else           run_tile(std::integral_constant<bool, false>{});
    }
  }

  if (tid == 63) out[b] = x1;   // wave 0, lane 63: ep[127][511]
}

}  // namespace

extern "C" void kernel_launch(void* const* d_in, const int* in_sizes, int n_in,
                              void* d_out, int out_size, void* d_ws, size_t ws_size,
                              hipStream_t stream) {
  const float* pred = (const float*)d_in[0];
  const float* R    = (const float*)d_in[1];
  const float* I    = (const float*)d_in[2];
  const int* target = (const int*)d_in[3];
  float* out = (float*)d_out;
  (void)in_sizes; (void)n_in; (void)out_size;

  const size_t needW = (size_t)kB * kNT * kNY * sizeof(float2);  // 64 MiB
  if (ws_size >= needW) {
    float2* W = (float2*)d_ws;
    gather_kernel<<<dim3(8, kB), dim3(256), 0, stream>>>(pred, R, I, target, W);
    dp_kernel<<<dim3(kB), dim3(64), 0, stream>>>(W, R, target, out);
  } else {
    ep_tiled_kernel<<<dim3(kB), dim3(512), 0, stream>>>(pred, R, I, target, out);
  }
}

// Round 9
// 140.137 us; speedup vs baseline: 1.8769x; 1.0020x over previous
//
#include <hip/hip_runtime.h>
#include <type_traits>

namespace {

constexpr int kNY    = 512;
constexpr int kNT    = 128;
constexpr int kC     = 128;
constexpr int kEOS   = 1;
constexpr int kB     = 128;
constexpr int kTJ    = 128;           // columns per tile (fused fallback)
constexpr int kNTile = kNY / kTJ;     // 4
constexpr int kLP    = 130;           // padded LDS stride (fallback)
constexpr int kJT    = 64;            // j-tile width (gather kernel)
constexpr int kLPg   = 65;            // padded stride (gather kernel)
constexpr size_t kPlane = (size_t)kB * kNT * kNY;   // floats per W plane (32 MiB)

// ---------------------------------------------------------------------------
// DPP helpers (pure builtins; HW-verified absmax 0.0 in R4/R6/R7/R8).
// ---------------------------------------------------------------------------
template <int CTRL, int RM>
__device__ __forceinline__ float dppf(float src, float old) {
  return __int_as_float(__builtin_amdgcn_update_dpp(
      __float_as_int(old), __float_as_int(src), CTRL, RM, 0xF, false));
}

// value of `v` in lane-1 (lane 0 -> 0.0f)
__device__ __forceinline__ float lane_prev(float v, int lane) {
  float s1  = dppf<0x111, 0xF>(v, 0.0f);   // row_shr:1 (within 16)
  float b15 = dppf<0x142, 0xA>(v, 0.0f);   // lanes 16-31<-15, 48-63<-47
  float b31 = dppf<0x143, 0x4>(v, 0.0f);   // lanes 32-47<-31
  float r = s1;
  r = (lane == 16 || lane == 48) ? b15 : r;
  r = (lane == 32) ? b31 : r;
  return r;
}

#define EP_SCAN_6STEPS                                           \
  EP_SCAN_STEP(0x111, 0xF)                                       \
  EP_SCAN_STEP(0x112, 0xF)                                       \
  EP_SCAN_STEP(0x114, 0xF)                                       \
  EP_SCAN_STEP(0x118, 0xF)                                       \
  EP_SCAN_STEP(0x142, 0xA)                                       \
  EP_SCAN_STEP(0x143, 0xC)

// 2-col variant (fused fallback kernel)
__device__ __forceinline__ void scan2(float A0, float B0, float Ap1, float Bp1,
                                      float& x0, float& x1, int lane) {
  float SA = Ap1, SB = Bp1;
#define EP_SCAN_STEP(CTRL, RM)                                   \
  { float a = dppf<CTRL, RM>(SA, 0.0f);                          \
    float bb = dppf<CTRL, RM>(SB, 1.0f);                         \
    SA = fmaf(SB, a, SA); SB *= bb; }
  EP_SCAN_6STEPS
#undef EP_SCAN_STEP
  const float carry = lane_prev(SA, lane);
  x0 = fmaf(B0, carry, A0);
  x1 = fmaf(Bp1, carry, Ap1);
}

// 8-col variant (dp kernel)
__device__ __forceinline__ void scan_apply8(const float (&Ap)[8],
                                            const float (&Bp)[8],
                                            float (&x)[8], float& xm1,
                                            int lane) {
  float SA = Ap[7], SB = Bp[7];
#define EP_SCAN_STEP(CTRL, RM)                                   \
  { float a = dppf<CTRL, RM>(SA, 0.0f);                          \
    float bb = dppf<CTRL, RM>(SB, 1.0f);                         \
    SA = fmaf(SB, a, SA); SB *= bb; }
  EP_SCAN_6STEPS
#undef EP_SCAN_STEP
  const float carry = lane_prev(SA, lane);
#pragma unroll
  for (int c = 0; c < 8; ++c) x[c] = fmaf(Bp[c], carry, Ap[c]);
  xm1 = carry;
}

// ===========================================================================
// PATH A: SoA gather (one plane per block via grid.z) + 8-col dp kernel.
// ===========================================================================
// grid (8, 128, 2): z=0 -> Wu = R0[j]*pred[b,j,t_i]; z=1 -> Wv = R1'[j]*I[...]
__global__ __launch_bounds__(256, 1) void gather_soa_kernel(
    const float* __restrict__ pred, const float* __restrict__ R,
    const float* __restrict__ I, const int* __restrict__ target,
    float* __restrict__ Wbase) {
  const int jt = blockIdx.x;        // 0..7
  const int b  = blockIdx.y;        // 0..127
  const int z  = blockIdx.z;        // 0: u-plane, 1: v-plane
  const int j0 = jt * kJT;
  const int tid = threadIdx.x;

  __shared__ float S[kC * kLPg];    // 33 KB: one array's [class][j] panel
  __shared__ int tgs[kNT];

  if (tid < kNT) tgs[tid] = target[b * kNT + tid];

  const float* src = z ? I : pred;
  float* dst = Wbase + (size_t)z * kPlane;

  {
    const int cg = (tid & 31) * 4;   // class offset 0..124
    int jl = tid >> 5;               // 0..7, step 8
    const float* Sb = src + ((size_t)b * kNY + j0) * kC;
#pragma unroll
    for (int it = 0; it < 8; ++it, jl += 8) {
      float4 a = *(const float4*)(Sb + (size_t)jl * kC + cg);
      S[(cg + 0) * kLPg + jl] = a.x;  S[(cg + 1) * kLPg + jl] = a.y;
      S[(cg + 2) * kLPg + jl] = a.z;  S[(cg + 3) * kLPg + jl] = a.w;
    }
  }
  const int l = tid & 63;            // lane
  const int w = tid >> 6;            // wave 0..3
  const int j = j0 + l;
  const float Rf = (z == 0)
      ? R[((size_t)b * kNY + j) * 3 + 0]
      : ((j == kNY - 1) ? 1.0f : R[((size_t)b * kNY + j) * 3 + 1]);
  __syncthreads();

  float* db = dst + (size_t)b * kNT * kNY + j;
#pragma unroll 4
  for (int p = 0; p < 32; ++p) {
    const int i = p * 4 + w;
    const int t = tgs[i];
    db[(size_t)i * kNY] = Rf * S[t * kLPg + l];
  }
}

// One DP row, 8 cols/lane, SoA quads: u[0..3]=qu0, u[4..7]=qu1, v likewise.
__device__ __forceinline__ void dp_row8(const float4& qu0, const float4& qu1,
                                        const float4& qv0, const float4& qv1,
                                        bool eos, bool lane0,
                                        const float (&R2m)[8], float (&x)[8],
                                        float& xm1, int lane) {
  float u[8], v[8];
  u[0] = qu0.x; u[1] = qu0.y; u[2] = qu0.z; u[3] = qu0.w;
  u[4] = qu1.x; u[5] = qu1.y; u[6] = qu1.z; u[7] = qu1.w;
  v[0] = qv0.x; v[1] = qv0.y; v[2] = qv0.z; v[3] = qv0.w;
  v[4] = qv1.x; v[5] = qv1.y; v[6] = qv1.z; v[7] = qv1.w;

  float A[8], Bv[8], Ap[8], Bp[8];
  const float um1 = lane_prev(u[7], lane);
  A[0]  = lane0 ? x[0] * v[1] : fmaf(x[0], v[0], xm1 * um1);
  Bv[0] = lane0 ? 0.0f : (eos ? 1.0f : R2m[0]);
#pragma unroll
  for (int c = 1; c < 8; ++c) {
    A[c]  = fmaf(x[c], v[c], x[c - 1] * u[c - 1]);
    Bv[c] = eos ? 1.0f : R2m[c];
  }
  Ap[0] = A[0]; Bp[0] = Bv[0];
#pragma unroll
  for (int c = 1; c < 8; ++c) {
    Ap[c] = fmaf(Bv[c], Ap[c - 1], A[c]);
    Bp[c] = Bv[c] * Bp[c - 1];
  }
  scan_apply8(Ap, Bp, x, xm1, lane);
}

__global__ __launch_bounds__(64, 1) void dp_kernel(
    const float* __restrict__ Wbase, const float* __restrict__ R,
    const int* __restrict__ target, float* __restrict__ out) {
  const int b = blockIdx.x;
  const int lane = threadIdx.x;
  const bool lane0 = (lane == 0);

  const int ta = target[b * kNT + lane];
  const int tb = target[b * kNT + 64 + lane];
  const unsigned long long eosLo = __ballot(ta == kEOS);
  const unsigned long long eosHi = __ballot(tb == kEOS);

  const float* Rb = R + (size_t)b * kNY * 3;
  float R2m[8], R2o[8];
#pragma unroll
  for (int c = 0; c < 8; ++c) R2o[c] = Rb[(lane * 8 + c) * 3 + 2];
  float r2m0 = 0.0f;
  if (lane != 0) r2m0 = Rb[(lane * 8 - 1) * 3 + 2];   // exec-masked
  R2m[0] = r2m0;
#pragma unroll
  for (int c = 1; c < 8; ++c) R2m[c] = R2o[c - 1];

  float x[8];
  float xm1 = 0.0f;

  // ---- row 0 ----
  {
    const bool eos0 = (eosLo & 1ull) != 0ull;
    float A[8], Bv[8], Ap[8], Bp[8];
    A[0]  = lane0 ? 1.0f : 0.0f;
    Bv[0] = lane0 ? 0.0f : (eos0 ? 1.0f : R2o[0]);
#pragma unroll
    for (int c = 1; c < 8; ++c) { A[c] = 0.0f; Bv[c] = eos0 ? 1.0f : R2o[c]; }
    Ap[0] = A[0]; Bp[0] = Bv[0];
#pragma unroll
    for (int c = 1; c < 8; ++c) {
      Ap[c] = fmaf(Bv[c], Ap[c - 1], A[c]);
      Bp[c] = Bv[c] * Bp[c - 1];
    }
    scan_apply8(Ap, Bp, x, xm1, lane);
  }

  auto eosAt = [&](int i) -> bool {
    return ((i < 64 ? (eosLo >> i) : (eosHi >> (i - 64))) & 1ull) != 0ull;
  };

  const float* pu = Wbase + (size_t)b * kNT * kNY + lane * 8;
  const float* pv = pu + kPlane;
  // depth-4 ring; loads for row r+4 issued BEFORE row r's compute.
  float4 ring[4][4];
#pragma unroll
  for (int r = 0; r < 4; ++r) {
    ring[r][0] = *(const float4*)(pu + (size_t)r * kNY);
    ring[r][1] = *(const float4*)(pu + (size_t)r * kNY + 4);
    ring[r][2] = *(const float4*)(pv + (size_t)r * kNY);
    ring[r][3] = *(const float4*)(pv + (size_t)r * kNY + 4);
  }

  auto step = [&](int r, float4 (&fr)[4]) {
    const float4 u0 = fr[0], u1 = fr[1], v0 = fr[2], v1 = fr[3];
    int nr = r + 4; if (nr > 126) nr = 126;
    fr[0] = *(const float4*)(pu + (size_t)nr * kNY);
    fr[1] = *(const float4*)(pu + (size_t)nr * kNY + 4);
    fr[2] = *(const float4*)(pv + (size_t)nr * kNY);
    fr[3] = *(const float4*)(pv + (size_t)nr * kNY + 4);
    dp_row8(u0, u1, v0, v1, eosAt(r + 1), lane0, R2m, x, xm1, lane);
  };

  for (int g = 0; g < 31; ++g) {     // rows 0..123
#pragma unroll
    for (int rr = 0; rr < 4; ++rr) step(g * 4 + rr, ring[rr]);
  }
#pragma unroll
  for (int rr = 0; rr < 3; ++rr) step(124 + rr, ring[rr]);  // rows 124..126

  if (lane == 63) out[b] = x[7];
}

// ===========================================================================
// PATH B fallback (R7 fused tiled kernel, HW-proven 127 us, absmax 0.0).
// ===========================================================================
__global__ __launch_bounds__(512, 1) void ep_tiled_kernel(
    const float* __restrict__ pred, const float* __restrict__ R,
    const float* __restrict__ I, const int* __restrict__ target,
    float* __restrict__ out) {
  const int b    = blockIdx.x;
  const int tid  = threadIdx.x;
  const int lane = tid & 63;
  const int wave = tid >> 6;
  const bool lane0 = (lane == 0);

  __shared__ float P[kC * kLP];
  __shared__ float Q[kC * kLP];
  __shared__ int   tgs[kNT];
  __shared__ float bndE[2][kNT];
  __shared__ float bndU[2][kNT];

  if (tid < kNT) tgs[tid] = target[b * kNT + tid];

  const int jl = tid >> 2;
  const int cq = (tid & 3) * 4;

  float x0 = 0.0f, x1 = 0.0f;
  unsigned long long eosLo = 0ull, eosHi = 0ull;
  if (wave == 0) {
    const int ta = target[b * kNT + lane];
    const int tb = target[b * kNT + 64 + lane];
    eosLo = __ballot(ta == kEOS);
    eosHi = __ballot(tb == kEOS);
  }

  float4 pa[8], qa[8];
  {
    const float* Pg = pred + ((size_t)b * kNY + jl) * kC + cq;
    const float* Ig = I    + ((size_t)b * kNY + jl) * kC + cq;
#pragma unroll
    for (int k = 0; k < 8; ++k) {
      pa[k] = *(const float4*)(Pg + k * 16);
      qa[k] = *(const float4*)(Ig + k * 16);
    }
  }

  for (int tile = 0; tile < kNTile; ++tile) {
    const int j0 = tile * kTJ;
    __syncthreads();

    {
      const int j = j0 + jl;
      const float R0 = R[((size_t)b * kNY + j) * 3 + 0];
      const float R1 = (j == kNY - 1) ? 1.0f : R[((size_t)b * kNY + j) * 3 + 1];
#pragma unroll
      for (int k = 0; k < 8; ++k) {
        const int c = cq + 16 * k;
        P[(c + 0) * kLP + jl] = R0 * pa[k].x;
        P[(c + 1) * kLP + jl] = R0 * pa[k].y;
        P[(c + 2) * kLP + jl] = R0 * pa[k].z;
        P[(c + 3) * kLP + jl] = R0 * pa[k].w;
        Q[(c + 0) * kLP + jl] = R1 * qa[k].x;
        Q[(c + 1) * kLP + jl] = R1 * qa[k].y;
        Q[(c + 2) * kLP + jl] = R1 * qa[k].z;
        Q[(c + 3) * kLP + jl] = R1 * qa[k].w;
      }
    }
    if (tile + 1 < kNTile) {
      const int jn = (tile + 1) * kTJ + jl;
      const float* Pg = pred + ((size_t)b * kNY + jn) * kC + cq;
      const float* Ig = I    + ((size_t)b * kNY + jn) * kC + cq;
#pragma unroll
      for (int k = 0; k < 8; ++k) {
        pa[k] = *(const float4*)(Pg + k * 16);
        qa[k] = *(const float4*)(Ig + k * 16);
      }
    }
    __syncthreads();

    if (wave == 0) {
      auto run_tile = [&](auto firstc) {
        constexpr bool FIRSTC = decltype(firstc)::value;
        const int wp = tile & 1;
        const int rp = wp ^ 1;
        const float* bE_r = bndE[rp];
        const float* bU_r = bndU[rp];
        float* bE_w = bndE[wp];
        float* bU_w = bndU[wp];

        const int ja = j0 + 2 * lane;
        const float* Rb = R + (size_t)b * kNY * 3;
        const float R2o0 = Rb[ja * 3 + 2];
        const float R2o1 = Rb[ja * 3 + 5];
        float R2m0 = 0.0f;
        if (ja >= 1) R2m0 = Rb[ja * 3 - 1];

        const bool eos0 = (eosLo & 1ull) != 0ull;
        {
          float B0 = eos0 ? 1.0f : R2o0;
          const float B1 = eos0 ? 1.0f : R2o1;
          float A0 = 0.0f;
          if (lane0) {
            if (FIRSTC) { A0 = 1.0f; B0 = 0.0f; }
            else        { A0 = B0 * bE_r[0]; }
          }
          const float Ap1 = B1 * A0;
          const float Bp1 = B1 * B0;
          scan2(A0, B0, Ap1, Bp1, x0, x1, lane);
          if (lane == 63) bE_w[0] = x1;
        }

        float2 U = *(const float2*)&P[tgs[0] * kLP + 2 * lane];
        float2 V = *(const float2*)&Q[tgs[0] * kLP + 2 * lane];
        int tA = tgs[1];
        float bE_prev = FIRSTC ? 0.0f : bE_r[0];
        float bE_cur  = FIRSTC ? 0.0f : bE_r[1];
        float bU_cur  = FIRSTC ? 0.0f : bU_r[1];
        unsigned long long m = eosLo >> 1;

        for (int i = 1; i < kNT; ++i) {
          const int ip = (i < kNT - 1) ? (i + 1) : (kNT - 1);
          const float2 Un = *(const float2*)&P[tA * kLP + 2 * lane];
          const float2 Vn = *(const float2*)&Q[tA * kLP + 2 * lane];
          const int tB = tgs[ip];
          const float bE_n = FIRSTC ? 0.0f : bE_r[ip];
          const float bU_n = FIRSTC ? 0.0f : bU_r[ip];

          const bool eos = (m & 1ull) != 0ull;
          float B0 = eos ? 1.0f : R2m0;
          const float B1 = eos ? 1.0f : R2o0;

          float pm1 = lane_prev(x1 * U.y, lane);
          if (lane0 && !FIRSTC) pm1 = bE_prev * bU_cur;
          float A0 = fmaf(x0, V.x, pm1);
          if (lane0) {
            if (FIRSTC) { A0 = x0 * V.y; B0 = 0.0f; }
            else        { A0 = fmaf(B0, bE_cur, A0); }
          }
          const float A1  = fmaf(x1, V.y, x0 * U.x);
          const float Ap1 = fmaf(B1, A0, A1);
          const float Bp1 = B1 * B0;
          scan2(A0, B0, Ap1, Bp1, x0, x1, lane);
          if (lane == 63) { bE_w[i] = x1; bU_w[i] = U.y; }

          bE_prev = bE_cur; bE_cur = bE_n; bU_cur = bU_n;
          U = Un; V = Vn; tA = tB;
          if (i == 63) m = eosHi; else m >>= 1;
        }
      };
      if (tile == 0) run_tile(std::integral_constant<bool, true>{});
      else           run_tile(std::integral_constant<bool, false>{});
    }
  }

  if (tid == 63) out[b] = x1;
}

}  // namespace

extern "C" void kernel_launch(void* const* d_in, const int* in_sizes, int n_in,
                              void* d_out, int out_size, void* d_ws, size_t ws_size,
                              hipStream_t stream) {
  const float* pred = (const float*)d_in[0];
  const float* R    = (const float*)d_in[1];
  const float* I    = (const float*)d_in[2];
  const int* target = (const int*)d_in[3];
  float* out = (float*)d_out;
  (void)in_sizes; (void)n_in; (void)out_size;

  const size_t needW = 2 * kPlane * sizeof(float);  // 64 MiB (two SoA planes)
  if (ws_size >= needW) {
    float* W = (float*)d_ws;
    gather_soa_kernel<<<dim3(8, kB, 2), dim3(256), 0, stream>>>(
        pred, R, I, target, W);
    dp_kernel<<<dim3(kB), dim3(64), 0, stream>>>(W, R, target, out);
  } else {
    ep_tiled_kernel<<<dim3(kB), dim3(512), 0, stream>>>(pred, R, I, target, out);
  }
}